// Round 2
// 249.897 us; speedup vs baseline: 1.0562x; 1.0562x over previous
//
#include <hip/hip_runtime.h>
#include <hip/hip_bf16.h>

// SGNHeadLSS — round 8: DENSE restructure, fixed.
// r7 post-mortem: failed (absmax 1.18, Output 0). Bug: sOut staged
// row-major [64][20] but the coalesced store read it channel-major
// [20][64] — pure layout mismatch, not a race. Fix: store loop reads
// sOut[vox*NCLS + ch]. Everything else identical to r7.
// r6->r7 theory: latency-bound (all pipes <30%); index-order iteration
// forced divergent x3d gathers and scattered stores. Dense voxel-order
// tiles: coalesced float4 loads, prior computed for all rows (MFMA ~5%
// util, waste free), masked rows selected via precomputed rank[] (d_ws),
// SSC staged in LDS -> fully coalesced store, aux store predicated.

#define NVOX 262144
#define NU   65536
#define NM   196608
#define CIN  128
#define CHALF 64
#define NCLS 20
#define TR   64
#define NBLK (NVOX / TR)  // 4096

#define SXS 136   // sX row stride in u16 (272B, 16B-aligned)
#define SHS 72    // sH row stride in u16 (144B, 16B-aligned)

// ws layout (u16 units), fragment order: [nt][kc][lane]*8
#define W1F  0       // nt4 kc4  -> 8192
#define W2F  8192    // nt8 kc2  -> 8192
#define SDBF 16384   // nt4 kc4  -> 8192
#define SSCF 24576   // nt2 kc2  -> 2048
#define AUXF 26624   // nt2 kc4  -> 4096
#define WS_WT 30720  // 61440 bytes of weights; rank[NVOX] int32 follows

typedef unsigned short u16;
typedef short    bf16x8 __attribute__((ext_vector_type(8)));
typedef float    f32x4  __attribute__((ext_vector_type(4)));

__device__ __forceinline__ u16 f2b(float f) {
    __hip_bfloat16 h = __float2bfloat16(f);
    return *(u16*)&h;
}

// B-frag layout: lane=q*16+n15 holds B[k=kc*32+q*8+j][n=nt*16+n15], j=0..7
__global__ void prep_weights(const float* __restrict__ w1,  const float* __restrict__ w2,
                             const float* __restrict__ sdbw,const float* __restrict__ sscw,
                             const float* __restrict__ auxw,
                             const int* __restrict__ uidx,  const int* __restrict__ midx,
                             u16* __restrict__ ws) {
    int i = blockIdx.x * blockDim.x + threadIdx.x;
    const int stride = gridDim.x * blockDim.x;
    int* __restrict__ rank = (int*)(ws + WS_WT);
    for (int t = i; t < NU; t += stride) rank[uidx[t]] = t;
    for (int t = i; t < NM; t += stride) rank[midx[t]] = -1;
    for (; i < WS_WT; i += stride) {
        float v;
        if (i < W2F) {                      // w1^frag: N=64, K=128
            int t = i, j = t & 7, lane = (t >> 3) & 63, kc = (t >> 9) & 3, nt = t >> 11;
            int k = kc*32 + (lane >> 4)*8 + j, n = nt*16 + (lane & 15);
            v = w1[k*CHALF + n];
        } else if (i < SDBF) {              // w2^frag: N=128, K=64
            int t = i - W2F, j = t & 7, lane = (t >> 3) & 63, kc = (t >> 9) & 1, nt = t >> 10;
            int k = kc*32 + (lane >> 4)*8 + j, n = nt*16 + (lane & 15);
            v = w2[k*CIN + n];
        } else if (i < SSCF) {              // sdb^frag: N=64, K=128
            int t = i - SDBF, j = t & 7, lane = (t >> 3) & 63, kc = (t >> 9) & 3, nt = t >> 11;
            int k = kc*32 + (lane >> 4)*8 + j, n = nt*16 + (lane & 15);
            v = sdbw[k*CHALF + n];
        } else if (i < AUXF) {              // ssc^frag: N=32(pad), K=64
            int t = i - SSCF, j = t & 7, lane = (t >> 3) & 63, kc = (t >> 9) & 1, nt = t >> 10;
            int k = kc*32 + (lane >> 4)*8 + j, n = nt*16 + (lane & 15);
            v = (n < NCLS) ? sscw[k*NCLS + n] : 0.f;
        } else {                            // aux^frag: N=32(pad), K=128
            int t = i - AUXF, j = t & 7, lane = (t >> 3) & 63, kc = (t >> 9) & 3, nt = t >> 11;
            int k = kc*32 + (lane >> 4)*8 + j, n = nt*16 + (lane & 15);
            v = (n < NCLS) ? auxw[k*NCLS + n] : 0.f;
        }
        ws[i] = f2b(v);
    }
}

__global__ __launch_bounds__(256, 3)
void sgn_mfma(const float* __restrict__ x3d,
              const float* __restrict__ b1,   const float* __restrict__ lng,
              const float* __restrict__ lnb,  const float* __restrict__ bb2,
              const float* __restrict__ sdbb, const float* __restrict__ sscb,
              const float* __restrict__ auxb,
              const int* __restrict__ rank,   const u16* __restrict__ wt,
              float* __restrict__ out)
{
    __shared__ __align__(16) u16 sX[TR * SXS];   // feats / vox     [r][k]
    __shared__ __align__(16) u16 sH[TR * SHS];   // h / d           [r][k]
    __shared__ __align__(16) u16 wbuf[8704];     // staged frags (17408 B); tail = sOut
    __shared__ int sRank[TR];

    const int tid = threadIdx.x;
    const int p0  = (int)blockIdx.x * TR;

    // ---- dense coalesced x3d load: 8x float4 per thread, all in flight ----
    const int g  = tid >> 4;        // 0..15 -> channel pair base
    const int v0 = (tid & 15) * 4;  // voxel quad within tile
    f32x4 va[4], vb[4];
    #pragma unroll
    for (int i = 0; i < 4; ++i) {
        const int c0 = i*32 + g*2;
        va[i] = *(const f32x4*)&x3d[(size_t)c0      * NVOX + p0 + v0];
        vb[i] = *(const f32x4*)&x3d[(size_t)(c0+1)  * NVOX + p0 + v0];
    }

    if (tid < TR) sRank[tid] = rank[p0 + tid];

    // ---- stage w1 frags (coalesced, overlaps x3d latency) ----
    {
        const uint4* src = (const uint4*)(wt + W1F);
        #pragma unroll
        for (int t = 0; t < 4; ++t)
            ((uint4*)wbuf)[tid + t*256] = src[tid + t*256];
    }

    // ---- pack -> sX[r][c]: pair-packed b32 writes (c0 even) ----
    #pragma unroll
    for (int i = 0; i < 4; ++i) {
        const int c0 = i*32 + g*2;
        #pragma unroll
        for (int j = 0; j < 4; ++j) {
            unsigned pk = (unsigned)f2b(va[i][j]) | ((unsigned)f2b(vb[i][j]) << 16);
            *(unsigned*)&sX[(v0 + j)*SXS + c0] = pk;
        }
    }
    __syncthreads();

    const int m0   = (tid >> 6) * 16;  // wave's 16-row slice
    const int lane = tid & 63;
    const int q    = lane >> 4;
    const int n15  = lane & 15;
    const int kq   = q * 8;

    // ---- GEMM1: feats[64x128] @ w1 -> LN -> leaky -> sH ----
    {
        f32x4 acc[4];
        #pragma unroll
        for (int nt = 0; nt < 4; ++nt) {
            const float b = b1[nt*16 + n15];
            acc[nt] = (f32x4){b, b, b, b};
        }
        #pragma unroll
        for (int kc = 0; kc < 4; ++kc) {
            const bf16x8 a = *(const bf16x8*)&sX[(m0 + n15) * SXS + kc*32 + kq];
            #pragma unroll
            for (int nt = 0; nt < 4; ++nt) {
                const bf16x8 b = *(const bf16x8*)&wbuf[((nt*4 + kc)*64 + lane)*8];
                acc[nt] = __builtin_amdgcn_mfma_f32_16x16x32_bf16(a, b, acc[nt], 0, 0, 0);
            }
        }
        float gv[4], ev[4];
        #pragma unroll
        for (int nt = 0; nt < 4; ++nt) { gv[nt] = lng[nt*16 + n15]; ev[nt] = lnb[nt*16 + n15]; }
        #pragma unroll
        for (int reg = 0; reg < 4; ++reg) {
            float s1 = acc[0][reg] + acc[1][reg] + acc[2][reg] + acc[3][reg];
            float s2 = acc[0][reg]*acc[0][reg] + acc[1][reg]*acc[1][reg]
                     + acc[2][reg]*acc[2][reg] + acc[3][reg]*acc[3][reg];
            #pragma unroll
            for (int m = 1; m <= 8; m <<= 1) {
                s1 += __shfl_xor(s1, m, 64);
                s2 += __shfl_xor(s2, m, 64);
            }
            const float mu  = s1 * (1.f/64.f);
            const float var = s2 * (1.f/64.f) - mu*mu;
            const float rs  = rsqrtf(var + 1e-5f);
            #pragma unroll
            for (int nt = 0; nt < 4; ++nt) {
                float h = (acc[nt][reg] - mu) * rs * gv[nt] + ev[nt];
                h = h > 0.f ? h : 0.01f*h;
                sH[(m0 + q*4 + reg) * SHS + nt*16 + n15] = f2b(h);
            }
        }
    }
    __syncthreads();                      // wbuf free + sH visible

    // ---- stage w2 frags ----
    #pragma unroll
    for (int t = 0; t < 4; ++t)
        ((uint4*)wbuf)[tid + t*256] = ((const uint4*)(wt + W2F))[tid + t*256];
    __syncthreads();

    // ---- GEMM2: h[64x64] @ w2 -> prior; overwrite MASKED rows of sX ----
    {
        f32x4 acc2[8];
        #pragma unroll
        for (int nt = 0; nt < 8; ++nt) {
            const float b = bb2[nt*16 + n15];
            acc2[nt] = (f32x4){b, b, b, b};
        }
        #pragma unroll
        for (int kc = 0; kc < 2; ++kc) {
            const bf16x8 a = *(const bf16x8*)&sH[(m0 + n15) * SHS + kc*32 + kq];
            #pragma unroll
            for (int nt = 0; nt < 8; ++nt) {
                const bf16x8 b = *(const bf16x8*)&wbuf[((nt*2 + kc)*64 + lane)*8];
                acc2[nt] = __builtin_amdgcn_mfma_f32_16x16x32_bf16(a, b, acc2[nt], 0, 0, 0);
            }
        }
        #pragma unroll
        for (int reg = 0; reg < 4; ++reg) {
            const int row = m0 + q*4 + reg;
            if (sRank[row] < 0) {          // masked -> vox = prior
                #pragma unroll
                for (int nt = 0; nt < 8; ++nt)
                    sX[row * SXS + nt*16 + n15] = f2b(acc2[nt][reg]);
            }                              // unmasked -> vox = feats (already there)
        }
    }
    __syncthreads();                      // wbuf free + sX select visible

    // ---- stage sdb frags ----
    #pragma unroll
    for (int t = 0; t < 4; ++t)
        ((uint4*)wbuf)[tid + t*256] = ((const uint4*)(wt + SDBF))[tid + t*256];
    __syncthreads();

    // ---- SDB: vox[64x128] @ sdb_w -> leaky -> sH (= d) ----
    {
        f32x4 accd[4];
        #pragma unroll
        for (int nt = 0; nt < 4; ++nt) {
            const float b = sdbb[nt*16 + n15];
            accd[nt] = (f32x4){b, b, b, b};
        }
        #pragma unroll
        for (int kc = 0; kc < 4; ++kc) {
            const bf16x8 a = *(const bf16x8*)&sX[(m0 + n15) * SXS + kc*32 + kq];
            #pragma unroll
            for (int nt = 0; nt < 4; ++nt) {
                const bf16x8 b = *(const bf16x8*)&wbuf[((nt*4 + kc)*64 + lane)*8];
                accd[nt] = __builtin_amdgcn_mfma_f32_16x16x32_bf16(a, b, accd[nt], 0, 0, 0);
            }
        }
        #pragma unroll
        for (int reg = 0; reg < 4; ++reg)
            #pragma unroll
            for (int nt = 0; nt < 4; ++nt) {
                float vv = accd[nt][reg];
                vv = vv > 0.f ? vv : 0.01f*vv;
                sH[(m0 + q*4 + reg) * SHS + nt*16 + n15] = f2b(vv);
            }
    }
    __syncthreads();                      // wbuf free + sH visible

    // ---- stage ssc + aux frags (12 KB) ----
    #pragma unroll
    for (int t = 0; t < 3; ++t)
        ((uint4*)wbuf)[tid + t*256] = ((const uint4*)(wt + SSCF))[tid + t*256];
    __syncthreads();

    float* sOut = (float*)(wbuf + 6144);   // 64x20 f32 = 5120B, after aux frags

    // ---- SSC: d[64x64] @ ssc_w[64x20] -> sOut (LDS, [row][ch]) ----
    {
        f32x4 accs[2];
        #pragma unroll
        for (int nt = 0; nt < 2; ++nt) {
            const int col = nt*16 + n15;
            const float b = (col < NCLS) ? sscb[col] : 0.f;
            accs[nt] = (f32x4){b, b, b, b};
        }
        #pragma unroll
        for (int kc = 0; kc < 2; ++kc) {
            const bf16x8 a = *(const bf16x8*)&sH[(m0 + n15) * SHS + kc*32 + kq];
            #pragma unroll
            for (int nt = 0; nt < 2; ++nt) {
                const bf16x8 b = *(const bf16x8*)&wbuf[((nt*2 + kc)*64 + lane)*8];
                accs[nt] = __builtin_amdgcn_mfma_f32_16x16x32_bf16(a, b, accs[nt], 0, 0, 0);
            }
        }
        #pragma unroll
        for (int reg = 0; reg < 4; ++reg) {
            const int row = m0 + q*4 + reg;
            sOut[row*NCLS + n15] = accs[0][reg];
            if (n15 < 4) sOut[row*NCLS + 16 + n15] = accs[1][reg];
        }
    }

    // ---- AUX: feats @ aux_w (all rows; only unmasked rows stored) ----
    f32x4 acca[2];
    {
        #pragma unroll
        for (int nt = 0; nt < 2; ++nt) {
            const int col = nt*16 + n15;
            const float b = (col < NCLS) ? auxb[col] : 0.f;
            acca[nt] = (f32x4){b, b, b, b};
        }
        #pragma unroll
        for (int kc = 0; kc < 4; ++kc) {
            const bf16x8 a = *(const bf16x8*)&sX[(m0 + n15) * SXS + kc*32 + kq];
            #pragma unroll
            for (int nt = 0; nt < 2; ++nt) {
                const bf16x8 b = *(const bf16x8*)&wbuf[2048 + ((nt*4 + kc)*64 + lane)*8];
                acca[nt] = __builtin_amdgcn_mfma_f32_16x16x32_bf16(a, b, acca[nt], 0, 0, 0);
            }
        }
    }
    __syncthreads();                      // sOut complete

    // ---- coalesced SSC store: out[ch][p0+vox] <- sOut[vox][ch] ----
    #pragma unroll
    for (int jj = 0; jj < 5; ++jj) {
        const int i = tid + jj*256;       // 1280 floats: i = ch*64 + vox
        out[(size_t)(i >> 6) * NVOX + p0 + (i & 63)] = sOut[(i & 63) * NCLS + (i >> 6)];
    }

    // ---- AUX store, predicated on unmasked; rank gives dense row ----
    {
        const size_t base = (size_t)NCLS * NVOX;
        #pragma unroll
        for (int reg = 0; reg < 4; ++reg) {
            const int row = m0 + q*4 + reg;
            const int rk  = sRank[row];
            if (rk >= 0) {
                out[base + (size_t)rk * NCLS + n15] = acca[0][reg];
                if (n15 < 4)
                    out[base + (size_t)rk * NCLS + 16 + n15] = acca[1][reg];
            }
        }
    }
}

extern "C" void kernel_launch(void* const* d_in, const int* in_sizes, int n_in,
                              void* d_out, int out_size, void* d_ws, size_t ws_size,
                              hipStream_t stream) {
    const float* x3d  = (const float*)d_in[0];
    const float* w1   = (const float*)d_in[1];
    const float* b1   = (const float*)d_in[2];
    const float* lng  = (const float*)d_in[3];
    const float* lnb  = (const float*)d_in[4];
    const float* w2   = (const float*)d_in[5];
    const float* bb2  = (const float*)d_in[6];
    const float* sdbw = (const float*)d_in[7];
    const float* sdbb = (const float*)d_in[8];
    const float* sscw = (const float*)d_in[9];
    const float* sscb = (const float*)d_in[10];
    const float* auxw = (const float*)d_in[11];
    const float* auxb = (const float*)d_in[12];
    const int*   uidx = (const int*)d_in[13];
    const int*   midx = (const int*)d_in[14];
    float* out = (float*)d_out;
    u16*   wt  = (u16*)d_ws;
    const int* rank = (const int*)((const char*)d_ws + WS_WT*2);

    hipLaunchKernelGGL(prep_weights, dim3(128), dim3(256), 0, stream,
                       w1, w2, sdbw, sscw, auxw, uidx, midx, wt);
    hipLaunchKernelGGL(sgn_mfma, dim3(NBLK), dim3(256), 0, stream,
                       x3d, b1, lng, lnb, bb2, sdbb, sscb, auxb,
                       rank, wt, out);
}